// Round 5
// baseline (924.116 us; speedup 1.0000x reference)
//
#include <hip/hip_runtime.h>
#include <hip/hip_fp16.h>

// ---------------------------------------------------------------------------
// GCN forward: h1 = relu(GCNConv(x, W1, b1)); h2 = relu(GCNConv(h1, W2, b2));
// out = h2 @ W_lin + b_lin
// N=100000, E=3200000, F_in=128, H=16, F_out=128.
// edge_index arrives as int32 [2*E]: row 0 = src, row 1 = dst.
//
// R5: CSR eliminated. Pipeline: bucket-count (256-node buckets) -> scan ->
// partition into bucket-contiguous packed (src<<8|dstlocal) runs -> per-bucket
// deg/dinv -> xform1 (g=fp16((x@W1)*dinv)) -> fused edge-parallel aggregation
// (block per bucket, LDS fp32 acc[256][17], 4-deep gather ILP) -> xform2 ->
// fused aggregation -> final GEMM. R4 lesson: 1024 buckets gave 32B partition
// runs -> 5.4x write amp; 391 buckets give 84B runs (~1.7x).
// ---------------------------------------------------------------------------

typedef int   v4i __attribute__((ext_vector_type(4)));
typedef float v4f __attribute__((ext_vector_type(4)));

#define NPB        256    // nodes per bucket
#define NPB_SHIFT  8
#define NB_MAX     512    // max buckets (LDS arrays)
#define PART_TILE  8192   // edges per partition block
#define PART_THR   512
#define PT_ITERS   (PART_TILE / 4 / PART_THR)   // = 4 quads/thread
#define AGG_TILE   1024   // pairs staged per aggregation tile

__global__ void k_zero_buckets(int* bucket_cnt) {
    bucket_cnt[threadIdx.x] = 0;
}

// Per-block LDS histogram of dst>>8, int4 loads, flushed once per block.
__global__ __launch_bounds__(256) void k_bucket_cnt(const int* __restrict__ ei,
                                                    int* __restrict__ bucket_cnt, int E) {
    __shared__ int h[NB_MAX];
    int t = threadIdx.x;
    for (int j = t; j < NB_MAX; j += 256) h[j] = 0;
    __syncthreads();
    const v4i* d4 = (const v4i*)(ei + E);
    int EQ = E >> 2;
    for (int q = blockIdx.x * 256 + t; q < EQ; q += gridDim.x * 256) {
        v4i dd = __builtin_nontemporal_load(d4 + q);
        atomicAdd(&h[dd.x >> NPB_SHIFT], 1);
        atomicAdd(&h[dd.y >> NPB_SHIFT], 1);
        atomicAdd(&h[dd.z >> NPB_SHIFT], 1);
        atomicAdd(&h[dd.w >> NPB_SHIFT], 1);
    }
    if (blockIdx.x == 0) {
        for (int e = (EQ << 2) + t; e < E; e += 256)
            atomicAdd(&h[ei[E + e] >> NPB_SHIFT], 1);
    }
    __syncthreads();
    for (int j = t; j < NB_MAX; j += 256)
        if (h[j]) atomicAdd(&bucket_cnt[j], h[j]);
}

// Exclusive scan of padded counts (pad to 16 pairs = 64B-aligned regions).
__global__ __launch_bounds__(NB_MAX) void k_bucket_scan(const int* __restrict__ bucket_cnt,
                                                        int* __restrict__ bucket_base,
                                                        int* __restrict__ bucket_cur) {
    __shared__ int s[NB_MAX];
    int t = threadIdx.x;
    int padded = (bucket_cnt[t] + 15) & ~15;
    s[t] = padded;
    __syncthreads();
    for (int off = 1; off < NB_MAX; off <<= 1) {
        int v = (t >= off) ? s[t - off] : 0;
        __syncthreads();
        s[t] += v;
        __syncthreads();
    }
    int excl = s[t] - padded;
    bucket_base[t] = excl;
    bucket_cur[t]  = excl;
}

// Partition edges into bucket-contiguous packed (src<<8 | dstlocal) runs.
__global__ __launch_bounds__(PART_THR) void k_partition(const int* __restrict__ ei,
                                                        int* __restrict__ bucket_cur,
                                                        int* __restrict__ pairs, int E) {
    __shared__ int h[NB_MAX];    // pass1: local hist; pass2: local cursor
    __shared__ int rb[NB_MAX];   // run base (absolute) per bucket
    int t = threadIdx.x;
    const v4i* s4 = (const v4i*)ei;
    const v4i* d4 = (const v4i*)(ei + E);
    int EQ = E >> 2;
    int q0 = blockIdx.x * (PART_TILE / 4);
    bool last = (blockIdx.x == gridDim.x - 1);
    v4i dsave[PT_ITERS];

    for (int j = t; j < NB_MAX; j += PART_THR) h[j] = 0;
    __syncthreads();
#pragma unroll
    for (int it = 0; it < PT_ITERS; ++it) {
        int q = q0 + it * PART_THR + t;
        v4i dd;
        if (q < EQ) {
            dd = __builtin_nontemporal_load(d4 + q);
            atomicAdd(&h[dd.x >> NPB_SHIFT], 1);
            atomicAdd(&h[dd.y >> NPB_SHIFT], 1);
            atomicAdd(&h[dd.z >> NPB_SHIFT], 1);
            atomicAdd(&h[dd.w >> NPB_SHIFT], 1);
        }
        dsave[it] = dd;
    }
    if (last) {
        for (int e = (EQ << 2) + t; e < E; e += PART_THR)
            atomicAdd(&h[ei[E + e] >> NPB_SHIFT], 1);
    }
    __syncthreads();
    for (int j = t; j < NB_MAX; j += PART_THR) {
        int c = h[j];
        rb[j] = c ? atomicAdd(&bucket_cur[j], c) : 0;
        h[j] = 0;
    }
    __syncthreads();
#pragma unroll
    for (int it = 0; it < PT_ITERS; ++it) {
        int q = q0 + it * PART_THR + t;
        if (q < EQ) {
            v4i ss = __builtin_nontemporal_load(s4 + q);
            v4i dd = dsave[it];
#pragma unroll
            for (int k = 0; k < 4; ++k) {
                int s = ss[k], d = dd[k];
                int b = d >> NPB_SHIFT;
                int pos = rb[b] + atomicAdd(&h[b], 1);
                pairs[pos] = (s << NPB_SHIFT) | (d & (NPB - 1));
            }
        }
    }
    if (last) {
        for (int e = (EQ << 2) + t; e < E; e += PART_THR) {
            int s = ei[e], d = ei[E + e];
            int b = d >> NPB_SHIFT;
            int pos = rb[b] + atomicAdd(&h[b], 1);
            pairs[pos] = (s << NPB_SHIFT) | (d & (NPB - 1));
        }
    }
}

// One block per bucket: LDS degree hist -> dinv (deg+1 for self-loop).
__global__ __launch_bounds__(256) void k_deg(const int* __restrict__ pairs,
                                             const int* __restrict__ bucket_cnt,
                                             const int* __restrict__ bucket_base,
                                             float* __restrict__ dinv, int N) {
    __shared__ int deg[NPB];
    int b = blockIdx.x, t = threadIdx.x;
    int n0 = b << NPB_SHIFT;
    int cnt  = bucket_cnt[b];
    int base = bucket_base[b];
    if (t < NPB) deg[t] = 0;
    __syncthreads();
    for (int i = t; i < cnt; i += 256)
        atomicAdd(&deg[pairs[base + i] & (NPB - 1)], 1);
    __syncthreads();
    if (t < NPB) {
        int n = n0 + t;
        if (n < N) dinv[n] = rsqrtf((float)(deg[t] + 1));
    }
}

// g[n,:] = fp16( (x[n,:] @ W1) * dinv[n] )   (128 -> 16), 16 nodes per block
__global__ __launch_bounds__(256) void k_xform1(const float* __restrict__ x,
                                                const float* __restrict__ W1,
                                                const float* __restrict__ dinv,
                                                __half* __restrict__ g, int N) {
    __shared__ float xs[16][132];
    __shared__ float ws[128 * 16];
    int t = threadIdx.x;
    int n0 = blockIdx.x * 16;
    const v4f* w4 = (const v4f*)W1;
    const v4f* x4 = (const v4f*)x;
    for (int idx = t; idx < 512; idx += 256) ((v4f*)ws)[idx] = w4[idx];
    for (int idx = t; idx < 512; idx += 256) {
        int r = idx >> 5, c4 = idx & 31;
        int n = n0 + r;
        v4f v = (n < N) ? x4[(size_t)n * 32 + c4] : (v4f)(0.f);
        *(v4f*)&xs[r][c4 * 4] = v;
    }
    __syncthreads();
    int node = t >> 4, f = t & 15;
    int n = n0 + node;
    if (n < N) {
        float sum = 0.f;
#pragma unroll
        for (int k = 0; k < 128; ++k) sum += xs[node][k] * ws[k * 16 + f];
        g[(size_t)n * 16 + f] = __float2half_rn(sum * dinv[n]);
    }
}

// Fused edge-parallel aggregation: one block per bucket.
// h[d,:] = relu( dinv[d] * (sum_{s->d} g[s,:] + g[d,:]) + bias )
__global__ __launch_bounds__(512) void k_aggr_fused(const __half* __restrict__ g,
                                                    const int* __restrict__ pairs,
                                                    const int* __restrict__ bucket_cnt,
                                                    const int* __restrict__ bucket_base,
                                                    const float* __restrict__ dinv,
                                                    const float* __restrict__ bias,
                                                    float* __restrict__ h, int N) {
    __shared__ float acc[NPB][17];   // stride 17: spreads LDS atomic banks
    __shared__ int   stage[AGG_TILE];
    int b = blockIdx.x, t = threadIdx.x;
    int n0 = b << NPB_SHIFT;
    int cnt  = bucket_cnt[b];
    int base = bucket_base[b];
    for (int i = t; i < NPB * 17; i += 512) ((float*)acc)[i] = 0.f;
    __syncthreads();
    int f2 = t & 7;        // feature half2 index
    int es = t >> 3;       // edge slot 0..63
    for (int off = 0; off < cnt; off += AGG_TILE) {
        int m = min(AGG_TILE, cnt - off);
        if (t < m) stage[t] = pairs[base + off + t];
        if (t + 512 < m) stage[t + 512] = pairs[base + off + t + 512];
        __syncthreads();
        for (int e0 = es; e0 < m; e0 += 256) {
            // gather phase: up to 4 independent loads in flight
            float2 fv[4]; int dl[4]; bool v[4];
#pragma unroll
            for (int j = 0; j < 4; ++j) {
                int e = e0 + j * 64;
                v[j] = (e < m);
                if (v[j]) {
                    int p = stage[e];
                    dl[j] = p & (NPB - 1);
                    fv[j] = __half22float2(
                        *(const __half2*)(g + ((size_t)(p >> NPB_SHIFT)) * 16 + 2 * f2));
                }
            }
#pragma unroll
            for (int j = 0; j < 4; ++j) {
                if (v[j]) {
                    atomicAdd(&acc[dl[j]][2 * f2], fv[j].x);
                    atomicAdd(&acc[dl[j]][2 * f2 + 1], fv[j].y);
                }
            }
        }
        __syncthreads();
    }
    // epilogue: self-loop + normalize + bias + relu
    float2* h2 = (float2*)h;
    for (int s = t; s < NPB * 8; s += 512) {
        int dl = s >> 3, ff = s & 7;
        int n = n0 + dl;
        if (n < N) {
            float2 self = __half22float2(*(const __half2*)(g + (size_t)n * 16 + 2 * ff));
            float di = dinv[n];
            float ox = fmaxf(di * (acc[dl][2 * ff]     + self.x) + bias[2 * ff],     0.f);
            float oy = fmaxf(di * (acc[dl][2 * ff + 1] + self.y) + bias[2 * ff + 1], 0.f);
            h2[(size_t)n * 8 + ff] = make_float2(ox, oy);
        }
    }
}

// g[n,:] = fp16( (h[n,:] @ W2) * dinv[n] )   (16 -> 16), half2 per thread
__global__ __launch_bounds__(256) void k_xform2(const float* __restrict__ h,
                                                const float* __restrict__ W2,
                                                const float* __restrict__ dinv,
                                                __half* __restrict__ g, int N) {
    __shared__ float ws[256];
    int t = threadIdx.x;
    ws[t] = W2[t];
    __syncthreads();
    int idx = blockIdx.x * 256 + t;
    if (idx < N * 8) {
        int n = idx >> 3, f2 = idx & 7;
        float sx = 0.f, sy = 0.f;
#pragma unroll
        for (int k = 0; k < 16; ++k) {
            float hv = h[(size_t)n * 16 + k];
            sx += hv * ws[k * 16 + 2 * f2];
            sy += hv * ws[k * 16 + 2 * f2 + 1];
        }
        float di = dinv[n];
        *(__half2*)(g + (size_t)n * 16 + 2 * f2) = __floats2half2_rn(sx * di, sy * di);
    }
}

// out[n,:] = h[n,:] @ W_lin + b_lin   (16 -> 128), 8 nodes/block, float4 out
__global__ __launch_bounds__(256) void k_final(const float* __restrict__ h,
                                               const float* __restrict__ Wl,
                                               const float* __restrict__ bl,
                                               float* __restrict__ out, int N) {
    __shared__ float ws[16 * 128];
    __shared__ float hs[8][16];
    int t = threadIdx.x;
    int n0 = blockIdx.x * 8;
    const v4f* w4 = (const v4f*)Wl;
    for (int idx = t; idx < 512; idx += 256) ((v4f*)ws)[idx] = w4[idx];
    if (t < 128) {
        int node = t >> 4, k = t & 15;
        int n = n0 + node;
        hs[node][k] = (n < N) ? h[(size_t)n * 16 + k] : 0.f;
    }
    __syncthreads();
    int node = t >> 5, f4 = t & 31;
    int n = n0 + node;
    if (n < N) {
        v4f a = *(const v4f*)(bl + 4 * f4);
#pragma unroll
        for (int k = 0; k < 16; ++k) {
            float hv = hs[node][k];
            a += hv * *((const v4f*)&ws[k * 128 + 4 * f4]);
        }
        __builtin_nontemporal_store(a, (v4f*)(out + (size_t)n * 128 + 4 * f4));
    }
}

extern "C" void kernel_launch(void* const* d_in, const int* in_sizes, int n_in,
                              void* d_out, int out_size, void* d_ws, size_t ws_size,
                              hipStream_t stream) {
    const float* x  = (const float*)d_in[0];
    const int*   ei = (const int*)d_in[1];
    const float* W1 = (const float*)d_in[2];
    const float* b1 = (const float*)d_in[3];
    const float* W2 = (const float*)d_in[4];
    const float* b2 = (const float*)d_in[5];
    const float* Wl = (const float*)d_in[6];
    const float* bl = (const float*)d_in[7];
    float*       out = (float*)d_out;

    const int N = in_sizes[0] / 128;
    const int E = in_sizes[1] / 2;
    const int NB = (N + NPB - 1) >> NPB_SHIFT;   // buckets used (<= NB_MAX)

    char* ws = (char*)d_ws;
    auto carve = [&](size_t bytes) {
        char* p = ws;
        ws += (bytes + 255) & ~(size_t)255;
        return p;
    };
    int*    bucket_cnt  = (int*)carve((size_t)NB_MAX * 4);
    int*    bucket_base = (int*)carve((size_t)NB_MAX * 4);
    int*    bucket_cur  = (int*)carve((size_t)NB_MAX * 4);
    float*  dinv        = (float*)carve((size_t)N * 4);
    int*    pairs       = (int*)carve(((size_t)E + 16 * NB_MAX) * 4);  // padded regions
    __half* gbuf        = (__half*)carve((size_t)N * 16 * 2);
    float*  hbuf        = (float*)carve((size_t)N * 16 * 4);
    (void)ws_size; (void)n_in; (void)out_size;

    const int TB = 256;
    // bucketed edge partition (shared by both layers)
    k_zero_buckets<<<1, NB_MAX, 0, stream>>>(bucket_cnt);
    k_bucket_cnt<<<512, TB, 0, stream>>>(ei, bucket_cnt, E);
    k_bucket_scan<<<1, NB_MAX, 0, stream>>>(bucket_cnt, bucket_base, bucket_cur);
    k_partition<<<(E + PART_TILE - 1) / PART_TILE, PART_THR, 0, stream>>>(ei, bucket_cur, pairs, E);
    k_deg<<<NB, TB, 0, stream>>>(pairs, bucket_cnt, bucket_base, dinv, N);
    // layer 1
    k_xform1<<<(N + 15) / 16, TB, 0, stream>>>(x, W1, dinv, gbuf, N);
    k_aggr_fused<<<NB, 512, 0, stream>>>(gbuf, pairs, bucket_cnt, bucket_base, dinv, b1, hbuf, N);
    // layer 2
    k_xform2<<<(N * 8 + TB - 1) / TB, TB, 0, stream>>>(hbuf, W2, dinv, gbuf, N);
    k_aggr_fused<<<NB, 512, 0, stream>>>(gbuf, pairs, bucket_cnt, bucket_base, dinv, b2, hbuf, N);
    // output projection
    k_final<<<(N + 7) / 8, TB, 0, stream>>>(hbuf, Wl, bl, out, N);
}

// Round 6
// 331.133 us; speedup vs baseline: 2.7908x; 2.7908x over previous
//
#include <hip/hip_runtime.h>
#include <hip/hip_fp16.h>

// ---------------------------------------------------------------------------
// GCN forward: h1 = relu(GCNConv(x, W1, b1)); h2 = relu(GCNConv(h1, W2, b2));
// out = h2 @ W_lin + b_lin
// N=100000, E=3200000, F_in=128, H=16, F_out=128.
// edge_index arrives as int32 [2*E]: row 0 = src, row 1 = dst.
//
// R6: bucket partition (256-node buckets, padded bases) -> per-bucket CSR
// build (int LDS atomics only) -> row-per-wave gather aggregation (16 groups
// x 4 lanes x 8B loads, shfl reduce, NO fp32 LDS atomics -- R5 lesson: fp32
// LDS atomicAdd compiles to a CAS retry loop, 357us of pure wait).
// g stored fp16 (3.2 MB, L2-resident) per R4. row_end explicit because
// padded bucket regions leave garbage between buckets.
// ---------------------------------------------------------------------------

typedef int   v4i __attribute__((ext_vector_type(4)));
typedef float v4f __attribute__((ext_vector_type(4)));

#define NPB        256    // nodes per bucket
#define NPB_SHIFT  8
#define NB_MAX     512    // max buckets
#define PART_TILE  8192   // edges per partition block
#define PART_THR   512
#define PT_ITERS   (PART_TILE / 4 / PART_THR)   // = 4 quads/thread

__global__ void k_zero_buckets(int* bucket_cnt) {
    bucket_cnt[threadIdx.x] = 0;
}

// Per-block LDS histogram of dst>>8, int4 loads, flushed once per block.
__global__ __launch_bounds__(256) void k_bucket_cnt(const int* __restrict__ ei,
                                                    int* __restrict__ bucket_cnt, int E) {
    __shared__ int h[NB_MAX];
    int t = threadIdx.x;
    for (int j = t; j < NB_MAX; j += 256) h[j] = 0;
    __syncthreads();
    const v4i* d4 = (const v4i*)(ei + E);
    int EQ = E >> 2;
    for (int q = blockIdx.x * 256 + t; q < EQ; q += gridDim.x * 256) {
        v4i dd = __builtin_nontemporal_load(d4 + q);
        atomicAdd(&h[dd.x >> NPB_SHIFT], 1);
        atomicAdd(&h[dd.y >> NPB_SHIFT], 1);
        atomicAdd(&h[dd.z >> NPB_SHIFT], 1);
        atomicAdd(&h[dd.w >> NPB_SHIFT], 1);
    }
    if (blockIdx.x == 0) {
        for (int e = (EQ << 2) + t; e < E; e += 256)
            atomicAdd(&h[ei[E + e] >> NPB_SHIFT], 1);
    }
    __syncthreads();
    for (int j = t; j < NB_MAX; j += 256)
        if (h[j]) atomicAdd(&bucket_cnt[j], h[j]);
}

// Exclusive scan of padded counts (pad to 16 pairs: 64B-aligned regions).
__global__ __launch_bounds__(NB_MAX) void k_bucket_scan(const int* __restrict__ bucket_cnt,
                                                        int* __restrict__ bucket_base,
                                                        int* __restrict__ bucket_cur) {
    __shared__ int s[NB_MAX];
    int t = threadIdx.x;
    int padded = (bucket_cnt[t] + 15) & ~15;
    s[t] = padded;
    __syncthreads();
    for (int off = 1; off < NB_MAX; off <<= 1) {
        int v = (t >= off) ? s[t - off] : 0;
        __syncthreads();
        s[t] += v;
        __syncthreads();
    }
    int excl = s[t] - padded;
    bucket_base[t] = excl;
    bucket_cur[t]  = excl;
}

// Partition edges into bucket-contiguous packed (src<<8 | dstlocal) runs.
__global__ __launch_bounds__(PART_THR) void k_partition(const int* __restrict__ ei,
                                                        int* __restrict__ bucket_cur,
                                                        int* __restrict__ pairs, int E) {
    __shared__ int h[NB_MAX];    // pass1: local hist; pass2: local cursor
    __shared__ int rb[NB_MAX];   // run base (absolute) per bucket
    int t = threadIdx.x;
    const v4i* s4 = (const v4i*)ei;
    const v4i* d4 = (const v4i*)(ei + E);
    int EQ = E >> 2;
    int q0 = blockIdx.x * (PART_TILE / 4);
    bool last = (blockIdx.x == gridDim.x - 1);
    v4i dsave[PT_ITERS];

    for (int j = t; j < NB_MAX; j += PART_THR) h[j] = 0;
    __syncthreads();
#pragma unroll
    for (int it = 0; it < PT_ITERS; ++it) {
        int q = q0 + it * PART_THR + t;
        v4i dd;
        if (q < EQ) {
            dd = __builtin_nontemporal_load(d4 + q);
            atomicAdd(&h[dd.x >> NPB_SHIFT], 1);
            atomicAdd(&h[dd.y >> NPB_SHIFT], 1);
            atomicAdd(&h[dd.z >> NPB_SHIFT], 1);
            atomicAdd(&h[dd.w >> NPB_SHIFT], 1);
        }
        dsave[it] = dd;
    }
    if (last) {
        for (int e = (EQ << 2) + t; e < E; e += PART_THR)
            atomicAdd(&h[ei[E + e] >> NPB_SHIFT], 1);
    }
    __syncthreads();
    for (int j = t; j < NB_MAX; j += PART_THR) {
        int c = h[j];
        rb[j] = c ? atomicAdd(&bucket_cur[j], c) : 0;
        h[j] = 0;
    }
    __syncthreads();
#pragma unroll
    for (int it = 0; it < PT_ITERS; ++it) {
        int q = q0 + it * PART_THR + t;
        if (q < EQ) {
            v4i ss = __builtin_nontemporal_load(s4 + q);
            v4i dd = dsave[it];
#pragma unroll
            for (int k = 0; k < 4; ++k) {
                int s = ss[k], d = dd[k];
                int b = d >> NPB_SHIFT;
                int pos = rb[b] + atomicAdd(&h[b], 1);
                pairs[pos] = (s << NPB_SHIFT) | (d & (NPB - 1));
            }
        }
    }
    if (last) {
        for (int e = (EQ << 2) + t; e < E; e += PART_THR) {
            int s = ei[e], d = ei[E + e];
            int b = d >> NPB_SHIFT;
            int pos = rb[b] + atomicAdd(&h[b], 1);
            pairs[pos] = (s << NPB_SHIFT) | (d & (NPB - 1));
        }
    }
}

// One block per bucket: int LDS deg hist -> scan -> row_start/row_end/dinv,
// then scatter csr_src within the bucket's contiguous region.
__global__ __launch_bounds__(256) void k_build(const int* __restrict__ pairs,
                                               const int* __restrict__ bucket_cnt,
                                               const int* __restrict__ bucket_base,
                                               int* __restrict__ row_start,
                                               int* __restrict__ row_end,
                                               float* __restrict__ dinv,
                                               int* __restrict__ csr_src, int N) {
    __shared__ int deg[NPB];
    __shared__ int scn[NPB];
    __shared__ int cur[NPB];
    int b = blockIdx.x, t = threadIdx.x;
    int n0 = b << NPB_SHIFT;
    int cnt  = bucket_cnt[b];
    int base = bucket_base[b];       // 16-aligned (padded scan)
    deg[t] = 0;
    __syncthreads();
    const v4i* p4 = (const v4i*)(pairs + base);
    int cq = cnt >> 2;
    for (int q = t; q < cq; q += 256) {
        v4i pp = p4[q];
        atomicAdd(&deg[pp.x & (NPB - 1)], 1);
        atomicAdd(&deg[pp.y & (NPB - 1)], 1);
        atomicAdd(&deg[pp.z & (NPB - 1)], 1);
        atomicAdd(&deg[pp.w & (NPB - 1)], 1);
    }
    for (int i = (cq << 2) + t; i < cnt; i += 256)
        atomicAdd(&deg[pairs[base + i] & (NPB - 1)], 1);
    __syncthreads();
    scn[t] = deg[t];
    __syncthreads();
    for (int off = 1; off < NPB; off <<= 1) {
        int v = (t >= off) ? scn[t - off] : 0;
        __syncthreads();
        scn[t] += v;
        __syncthreads();
    }
    {
        int n = n0 + t;
        if (n < N) {
            int incl = scn[t];
            int excl = incl - deg[t];
            row_start[n] = base + excl;
            row_end[n]   = base + incl;
            cur[t]       = base + excl;
            dinv[n]      = rsqrtf((float)(deg[t] + 1));  // +1 self-loop
        }
    }
    __syncthreads();
    for (int q = t; q < cq; q += 256) {
        v4i pp = p4[q];
#pragma unroll
        for (int k = 0; k < 4; ++k) {
            int p = pp[k];
            int pos = atomicAdd(&cur[p & (NPB - 1)], 1);
            csr_src[pos] = p >> NPB_SHIFT;
        }
    }
    for (int i = (cq << 2) + t; i < cnt; i += 256) {
        int p = pairs[base + i];
        int pos = atomicAdd(&cur[p & (NPB - 1)], 1);
        csr_src[pos] = p >> NPB_SHIFT;
    }
}

// g[n,:] = fp16( (x[n,:] @ W1) * dinv[n] )   (128 -> 16), 16 nodes per block
__global__ __launch_bounds__(256) void k_xform1(const float* __restrict__ x,
                                                const float* __restrict__ W1,
                                                const float* __restrict__ dinv,
                                                __half* __restrict__ g, int N) {
    __shared__ float xs[16][132];
    __shared__ float ws[128 * 16];
    int t = threadIdx.x;
    int n0 = blockIdx.x * 16;
    const v4f* w4 = (const v4f*)W1;
    const v4f* x4 = (const v4f*)x;
    for (int idx = t; idx < 512; idx += 256) ((v4f*)ws)[idx] = w4[idx];
    for (int idx = t; idx < 512; idx += 256) {
        int r = idx >> 5, c4 = idx & 31;
        int n = n0 + r;
        v4f v = (n < N) ? x4[(size_t)n * 32 + c4] : (v4f)(0.f);
        *(v4f*)&xs[r][c4 * 4] = v;
    }
    __syncthreads();
    int node = t >> 4, f = t & 15;
    int n = n0 + node;
    if (n < N) {
        float sum = 0.f;
#pragma unroll
        for (int k = 0; k < 128; ++k) sum += xs[node][k] * ws[k * 16 + f];
        g[(size_t)n * 16 + f] = __float2half_rn(sum * dinv[n]);
    }
}

// h[d,:] = relu( dinv[d] * (sum_{s in row d} g[s,:] + g[d,:]) + bias )
// one wave per node: 16 edge-groups x 4 lanes x 8B (4 features) each.
__global__ __launch_bounds__(256) void k_aggr(const __half* __restrict__ g,
                                              const int* __restrict__ row_start,
                                              const int* __restrict__ row_end,
                                              const int* __restrict__ csr_src,
                                              const float* __restrict__ dinv,
                                              const float* __restrict__ bias,
                                              float* __restrict__ h, int N) {
    int wave = threadIdx.x >> 6;
    int lane = threadIdx.x & 63;
    int d = blockIdx.x * 4 + wave;
    if (d >= N) return;
    int grp = lane >> 2, f4 = lane & 3;
    int s0 = row_start[d], s1 = row_end[d];
    float ax = 0.f, ay = 0.f, az = 0.f, aw = 0.f;
    for (int i = s0 + grp; i < s1; i += 16) {
        int s = __builtin_nontemporal_load(csr_src + i);
        uint2 raw = *(const uint2*)(g + (size_t)s * 16 + 4 * f4);
        float2 f0 = __half22float2(*(__half2*)&raw.x);
        float2 f1 = __half22float2(*(__half2*)&raw.y);
        ax += f0.x; ay += f0.y; az += f1.x; aw += f1.y;
    }
#pragma unroll
    for (int off = 4; off <= 32; off <<= 1) {
        ax += __shfl_xor(ax, off);
        ay += __shfl_xor(ay, off);
        az += __shfl_xor(az, off);
        aw += __shfl_xor(aw, off);
    }
    if (grp == 0) {
        uint2 raw = *(const uint2*)(g + (size_t)d * 16 + 4 * f4);
        float2 s0f = __half22float2(*(__half2*)&raw.x);
        float2 s1f = __half22float2(*(__half2*)&raw.y);
        float di = dinv[d];
        v4f bb = *(const v4f*)(bias + 4 * f4);
        v4f o;
        o.x = fmaxf(di * (ax + s0f.x) + bb.x, 0.f);
        o.y = fmaxf(di * (ay + s0f.y) + bb.y, 0.f);
        o.z = fmaxf(di * (az + s1f.x) + bb.z, 0.f);
        o.w = fmaxf(di * (aw + s1f.y) + bb.w, 0.f);
        __builtin_nontemporal_store(o, (v4f*)(h + (size_t)d * 16 + 4 * f4));
    }
}

// g[n,:] = fp16( (h[n,:] @ W2) * dinv[n] )   (16 -> 16), half2 per thread
__global__ __launch_bounds__(256) void k_xform2(const float* __restrict__ h,
                                                const float* __restrict__ W2,
                                                const float* __restrict__ dinv,
                                                __half* __restrict__ g, int N) {
    __shared__ float ws[256];
    int t = threadIdx.x;
    ws[t] = W2[t];
    __syncthreads();
    int idx = blockIdx.x * 256 + t;
    if (idx < N * 8) {
        int n = idx >> 3, f2 = idx & 7;
        float sx = 0.f, sy = 0.f;
#pragma unroll
        for (int k = 0; k < 16; ++k) {
            float hv = h[(size_t)n * 16 + k];
            sx += hv * ws[k * 16 + 2 * f2];
            sy += hv * ws[k * 16 + 2 * f2 + 1];
        }
        float di = dinv[n];
        *(__half2*)(g + (size_t)n * 16 + 2 * f2) = __floats2half2_rn(sx * di, sy * di);
    }
}

// out[n,:] = h[n,:] @ W_lin + b_lin   (16 -> 128), 8 nodes/block, float4 out
__global__ __launch_bounds__(256) void k_final(const float* __restrict__ h,
                                               const float* __restrict__ Wl,
                                               const float* __restrict__ bl,
                                               float* __restrict__ out, int N) {
    __shared__ float ws[16 * 128];
    __shared__ float hs[8][16];
    int t = threadIdx.x;
    int n0 = blockIdx.x * 8;
    const v4f* w4 = (const v4f*)Wl;
    for (int idx = t; idx < 512; idx += 256) ((v4f*)ws)[idx] = w4[idx];
    if (t < 128) {
        int node = t >> 4, k = t & 15;
        int n = n0 + node;
        hs[node][k] = (n < N) ? h[(size_t)n * 16 + k] : 0.f;
    }
    __syncthreads();
    int node = t >> 5, f4 = t & 31;
    int n = n0 + node;
    if (n < N) {
        v4f a = *(const v4f*)(bl + 4 * f4);
#pragma unroll
        for (int k = 0; k < 16; ++k) {
            float hv = hs[node][k];
            a += hv * *((const v4f*)&ws[k * 128 + 4 * f4]);
        }
        __builtin_nontemporal_store(a, (v4f*)(out + (size_t)n * 128 + 4 * f4));
    }
}

extern "C" void kernel_launch(void* const* d_in, const int* in_sizes, int n_in,
                              void* d_out, int out_size, void* d_ws, size_t ws_size,
                              hipStream_t stream) {
    const float* x  = (const float*)d_in[0];
    const int*   ei = (const int*)d_in[1];
    const float* W1 = (const float*)d_in[2];
    const float* b1 = (const float*)d_in[3];
    const float* W2 = (const float*)d_in[4];
    const float* b2 = (const float*)d_in[5];
    const float* Wl = (const float*)d_in[6];
    const float* bl = (const float*)d_in[7];
    float*       out = (float*)d_out;

    const int N = in_sizes[0] / 128;
    const int E = in_sizes[1] / 2;
    const int NB = (N + NPB - 1) >> NPB_SHIFT;   // buckets used (<= NB_MAX)

    char* ws = (char*)d_ws;
    auto carve = [&](size_t bytes) {
        char* p = ws;
        ws += (bytes + 255) & ~(size_t)255;
        return p;
    };
    int*   bucket_cnt  = (int*)carve((size_t)NB_MAX * 4);
    int*   bucket_base = (int*)carve((size_t)NB_MAX * 4);
    int*   bucket_cur  = (int*)carve((size_t)NB_MAX * 4);
    float* dinv        = (float*)carve((size_t)N * 4);
    int*   row_start   = (int*)carve((size_t)N * 4);
    int*   row_end     = (int*)carve((size_t)N * 4);
    int*   csr_src     = (int*)carve(((size_t)E + 16 * NB_MAX) * 4);
    // pairs dead after k_build -> alias g(fp16)+h(fp32) onto it
    size_t pairs_bytes = ((size_t)E + 16 * NB_MAX) * 4;
    size_t gh_bytes    = ((size_t)N * 16 * 2 + 255 & ~(size_t)255) + (size_t)N * 16 * 4;
    size_t union_bytes = pairs_bytes > gh_bytes ? pairs_bytes : gh_bytes;
    int*    pairs = (int*)carve(union_bytes);
    __half* gbuf  = (__half*)pairs;
    float*  hbuf  = (float*)((char*)pairs + ((size_t)N * 16 * 2 + 255 & ~(size_t)255));
    (void)ws_size; (void)n_in; (void)out_size;

    const int TB = 256;
    // bucketed edge partition + CSR (shared by both layers)
    k_zero_buckets<<<1, NB_MAX, 0, stream>>>(bucket_cnt);
    k_bucket_cnt<<<512, TB, 0, stream>>>(ei, bucket_cnt, E);
    k_bucket_scan<<<1, NB_MAX, 0, stream>>>(bucket_cnt, bucket_base, bucket_cur);
    k_partition<<<(E + PART_TILE - 1) / PART_TILE, PART_THR, 0, stream>>>(ei, bucket_cur, pairs, E);
    k_build<<<NB, TB, 0, stream>>>(pairs, bucket_cnt, bucket_base, row_start, row_end, dinv, csr_src, N);
    // layer 1
    k_xform1<<<(N + 15) / 16, TB, 0, stream>>>(x, W1, dinv, gbuf, N);
    k_aggr<<<(N + 3) / 4, TB, 0, stream>>>(gbuf, row_start, row_end, csr_src, dinv, b1, hbuf, N);
    // layer 2
    k_xform2<<<(N * 8 + TB - 1) / TB, TB, 0, stream>>>(hbuf, W2, dinv, gbuf, N);
    k_aggr<<<(N + 3) / 4, TB, 0, stream>>>(gbuf, row_start, row_end, csr_src, dinv, b2, hbuf, N);
    // output projection
    k_final<<<(N + 7) / 8, TB, 0, stream>>>(hbuf, Wl, bl, out, N);
}

// Round 7
// 322.698 us; speedup vs baseline: 2.8637x; 1.0261x over previous
//
#include <hip/hip_runtime.h>
#include <hip/hip_fp16.h>

// ---------------------------------------------------------------------------
// GCN forward: h1 = relu(GCNConv(x, W1, b1)); h2 = relu(GCNConv(h1, W2, b2));
// out = h2 @ W_lin + b_lin
// N=100000, E=3200000, F_in=128, H=16, F_out=128.
// edge_index arrives as int32 [2*E]: row 0 = src, row 1 = dst.
//
// R7 pipeline (8 kernels):
//   zero -> bucket_cnt -> scan -> partition(1024thr) -> build(CSR per bucket)
//   -> xform1 (g1 = fp16((x@W1)*dinv))
//   -> aggr1  (gather+reduce, epilogue fuses relu+W2+dinv -> g2 fp16)
//   -> aggr2  (gather+reduce, epilogue fuses relu+W_lin+bias -> out fp32)
// Key lessons baked in: no fp32 LDS atomics (R5: CAS loop = 357us stall);
// fp16 g keeps gathers L2-resident (R4); xor-butterfly leaves full sums in
// ALL lanes -> epilogue GEMM fusion via shfl broadcast (R7).
// ---------------------------------------------------------------------------

typedef int   v4i __attribute__((ext_vector_type(4)));
typedef float v4f __attribute__((ext_vector_type(4)));
typedef float v2f __attribute__((ext_vector_type(2)));

#define NPB        256    // nodes per bucket
#define NPB_SHIFT  8
#define NB_MAX     512    // max buckets
#define PART_TILE  8192   // edges per partition block
#define PART_THR   1024
#define PT_ITERS   (PART_TILE / 4 / PART_THR)   // = 2 quads/thread

__global__ void k_zero_buckets(int* bucket_cnt) {
    bucket_cnt[threadIdx.x] = 0;
}

// Per-block LDS histogram of dst>>8, int4 loads, flushed once per block.
__global__ __launch_bounds__(256) void k_bucket_cnt(const int* __restrict__ ei,
                                                    int* __restrict__ bucket_cnt, int E) {
    __shared__ int h[NB_MAX];
    int t = threadIdx.x;
    for (int j = t; j < NB_MAX; j += 256) h[j] = 0;
    __syncthreads();
    const v4i* d4 = (const v4i*)(ei + E);
    int EQ = E >> 2;
    for (int q = blockIdx.x * 256 + t; q < EQ; q += gridDim.x * 256) {
        v4i dd = __builtin_nontemporal_load(d4 + q);
        atomicAdd(&h[dd.x >> NPB_SHIFT], 1);
        atomicAdd(&h[dd.y >> NPB_SHIFT], 1);
        atomicAdd(&h[dd.z >> NPB_SHIFT], 1);
        atomicAdd(&h[dd.w >> NPB_SHIFT], 1);
    }
    if (blockIdx.x == 0) {
        for (int e = (EQ << 2) + t; e < E; e += 256)
            atomicAdd(&h[ei[E + e] >> NPB_SHIFT], 1);
    }
    __syncthreads();
    for (int j = t; j < NB_MAX; j += 256)
        if (h[j]) atomicAdd(&bucket_cnt[j], h[j]);
}

// Exclusive scan of padded counts (pad to 16 pairs: 64B-aligned regions).
__global__ __launch_bounds__(NB_MAX) void k_bucket_scan(const int* __restrict__ bucket_cnt,
                                                        int* __restrict__ bucket_base,
                                                        int* __restrict__ bucket_cur) {
    __shared__ int s[NB_MAX];
    int t = threadIdx.x;
    int padded = (bucket_cnt[t] + 15) & ~15;
    s[t] = padded;
    __syncthreads();
    for (int off = 1; off < NB_MAX; off <<= 1) {
        int v = (t >= off) ? s[t - off] : 0;
        __syncthreads();
        s[t] += v;
        __syncthreads();
    }
    int excl = s[t] - padded;
    bucket_base[t] = excl;
    bucket_cur[t]  = excl;
}

// Partition edges into bucket-contiguous packed (src<<8 | dstlocal) runs.
__global__ __launch_bounds__(PART_THR) void k_partition(const int* __restrict__ ei,
                                                        int* __restrict__ bucket_cur,
                                                        int* __restrict__ pairs, int E) {
    __shared__ int h[NB_MAX];    // pass1: local hist; pass2: local cursor
    __shared__ int rb[NB_MAX];   // run base (absolute) per bucket
    int t = threadIdx.x;
    const v4i* s4 = (const v4i*)ei;
    const v4i* d4 = (const v4i*)(ei + E);
    int EQ = E >> 2;
    int q0 = blockIdx.x * (PART_TILE / 4);
    bool last = (blockIdx.x == gridDim.x - 1);
    v4i dsave[PT_ITERS];

    for (int j = t; j < NB_MAX; j += PART_THR) h[j] = 0;
    __syncthreads();
#pragma unroll
    for (int it = 0; it < PT_ITERS; ++it) {
        int q = q0 + it * PART_THR + t;
        v4i dd;
        if (q < EQ) {
            dd = __builtin_nontemporal_load(d4 + q);
            atomicAdd(&h[dd.x >> NPB_SHIFT], 1);
            atomicAdd(&h[dd.y >> NPB_SHIFT], 1);
            atomicAdd(&h[dd.z >> NPB_SHIFT], 1);
            atomicAdd(&h[dd.w >> NPB_SHIFT], 1);
        }
        dsave[it] = dd;
    }
    if (last) {
        for (int e = (EQ << 2) + t; e < E; e += PART_THR)
            atomicAdd(&h[ei[E + e] >> NPB_SHIFT], 1);
    }
    __syncthreads();
    for (int j = t; j < NB_MAX; j += PART_THR) {
        int c = h[j];
        rb[j] = c ? atomicAdd(&bucket_cur[j], c) : 0;
        h[j] = 0;
    }
    __syncthreads();
#pragma unroll
    for (int it = 0; it < PT_ITERS; ++it) {
        int q = q0 + it * PART_THR + t;
        if (q < EQ) {
            v4i ss = __builtin_nontemporal_load(s4 + q);
            v4i dd = dsave[it];
#pragma unroll
            for (int k = 0; k < 4; ++k) {
                int s = ss[k], d = dd[k];
                int b = d >> NPB_SHIFT;
                int pos = rb[b] + atomicAdd(&h[b], 1);
                pairs[pos] = (s << NPB_SHIFT) | (d & (NPB - 1));
            }
        }
    }
    if (last) {
        for (int e = (EQ << 2) + t; e < E; e += PART_THR) {
            int s = ei[e], d = ei[E + e];
            int b = d >> NPB_SHIFT;
            int pos = rb[b] + atomicAdd(&h[b], 1);
            pairs[pos] = (s << NPB_SHIFT) | (d & (NPB - 1));
        }
    }
}

// One block per bucket: int LDS deg hist -> scan -> row_start/row_end/dinv,
// then scatter csr_src within the bucket's contiguous region.
__global__ __launch_bounds__(256) void k_build(const int* __restrict__ pairs,
                                               const int* __restrict__ bucket_cnt,
                                               const int* __restrict__ bucket_base,
                                               int* __restrict__ row_start,
                                               int* __restrict__ row_end,
                                               float* __restrict__ dinv,
                                               int* __restrict__ csr_src, int N) {
    __shared__ int deg[NPB];
    __shared__ int scn[NPB];
    __shared__ int cur[NPB];
    int b = blockIdx.x, t = threadIdx.x;
    int n0 = b << NPB_SHIFT;
    int cnt  = bucket_cnt[b];
    int base = bucket_base[b];       // 16-aligned (padded scan)
    deg[t] = 0;
    __syncthreads();
    const v4i* p4 = (const v4i*)(pairs + base);
    int cq = cnt >> 2;
    for (int q = t; q < cq; q += 256) {
        v4i pp = p4[q];
        atomicAdd(&deg[pp.x & (NPB - 1)], 1);
        atomicAdd(&deg[pp.y & (NPB - 1)], 1);
        atomicAdd(&deg[pp.z & (NPB - 1)], 1);
        atomicAdd(&deg[pp.w & (NPB - 1)], 1);
    }
    for (int i = (cq << 2) + t; i < cnt; i += 256)
        atomicAdd(&deg[pairs[base + i] & (NPB - 1)], 1);
    __syncthreads();
    scn[t] = deg[t];
    __syncthreads();
    for (int off = 1; off < NPB; off <<= 1) {
        int v = (t >= off) ? scn[t - off] : 0;
        __syncthreads();
        scn[t] += v;
        __syncthreads();
    }
    {
        int n = n0 + t;
        if (n < N) {
            int incl = scn[t];
            int excl = incl - deg[t];
            row_start[n] = base + excl;
            row_end[n]   = base + incl;
            cur[t]       = base + excl;
            dinv[n]      = rsqrtf((float)(deg[t] + 1));  // +1 self-loop
        }
    }
    __syncthreads();
    for (int q = t; q < cq; q += 256) {
        v4i pp = p4[q];
#pragma unroll
        for (int k = 0; k < 4; ++k) {
            int p = pp[k];
            int pos = atomicAdd(&cur[p & (NPB - 1)], 1);
            csr_src[pos] = p >> NPB_SHIFT;
        }
    }
    for (int i = (cq << 2) + t; i < cnt; i += 256) {
        int p = pairs[base + i];
        int pos = atomicAdd(&cur[p & (NPB - 1)], 1);
        csr_src[pos] = p >> NPB_SHIFT;
    }
}

// g1[n,:] = fp16( (x[n,:] @ W1) * dinv[n] )   (128 -> 16), 16 nodes per block
__global__ __launch_bounds__(256) void k_xform1(const float* __restrict__ x,
                                                const float* __restrict__ W1,
                                                const float* __restrict__ dinv,
                                                __half* __restrict__ g, int N) {
    __shared__ float xs[16][132];
    __shared__ float ws[128 * 16];
    int t = threadIdx.x;
    int n0 = blockIdx.x * 16;
    const v4f* w4 = (const v4f*)W1;
    const v4f* x4 = (const v4f*)x;
    for (int idx = t; idx < 512; idx += 256) ((v4f*)ws)[idx] = w4[idx];
    for (int idx = t; idx < 512; idx += 256) {
        int r = idx >> 5, c4 = idx & 31;
        int n = n0 + r;
        v4f v = (n < N) ? x4[(size_t)n * 32 + c4] : (v4f)(0.f);
        *(v4f*)&xs[r][c4 * 4] = v;
    }
    __syncthreads();
    int node = t >> 4, f = t & 15;
    int n = n0 + node;
    if (n < N) {
        float sum = 0.f;
#pragma unroll
        for (int k = 0; k < 128; ++k) sum += xs[node][k] * ws[k * 16 + f];
        g[(size_t)n * 16 + f] = __float2half_rn(sum * dinv[n]);
    }
}

// Layer-1 aggregation + fused xform2.
// One wave per node d: 16 groups x 4 lanes gather g1 rows (2-deep ILP),
// xor-butterfly leaves full sums in all lanes, epilogue computes
// h = relu(dinv*(sum+self)+b1), then g2 = fp16((h@W2)*dinv) via shfl bcast.
__global__ __launch_bounds__(256) void k_aggr1(const __half* __restrict__ g,
                                               const int* __restrict__ row_start,
                                               const int* __restrict__ row_end,
                                               const int* __restrict__ csr_src,
                                               const float* __restrict__ dinv,
                                               const float* __restrict__ b1,
                                               const float* __restrict__ W2,
                                               __half* __restrict__ g2, int N) {
    __shared__ float w2s[256];
    __shared__ float b1s[16];
    int t = threadIdx.x;
    w2s[t] = W2[t];
    if (t < 16) b1s[t] = b1[t];
    __syncthreads();
    int wave = t >> 6, lane = t & 63;
    int d = blockIdx.x * 4 + wave;
    if (d >= N) return;
    int grp = lane >> 2, f4 = lane & 3;
    int s0 = row_start[d], s1 = row_end[d];
    float ax = 0.f, ay = 0.f, az = 0.f, aw = 0.f;
    for (int i = s0 + grp; i < s1; i += 32) {
        int sa = __builtin_nontemporal_load(csr_src + i);
        int ib = i + 16;
        bool two = (ib < s1);
        int sb = two ? __builtin_nontemporal_load(csr_src + ib) : 0;
        uint2 ra = *(const uint2*)(g + (size_t)sa * 16 + 4 * f4);
        uint2 rb;
        if (two) rb = *(const uint2*)(g + (size_t)sb * 16 + 4 * f4);
        float2 a0 = __half22float2(*(__half2*)&ra.x);
        float2 a1 = __half22float2(*(__half2*)&ra.y);
        ax += a0.x; ay += a0.y; az += a1.x; aw += a1.y;
        if (two) {
            float2 c0 = __half22float2(*(__half2*)&rb.x);
            float2 c1 = __half22float2(*(__half2*)&rb.y);
            ax += c0.x; ay += c0.y; az += c1.x; aw += c1.y;
        }
    }
#pragma unroll
    for (int off = 4; off <= 32; off <<= 1) {
        ax += __shfl_xor(ax, off);
        ay += __shfl_xor(ay, off);
        az += __shfl_xor(az, off);
        aw += __shfl_xor(aw, off);
    }
    // all lanes hold full sums for features 4*f4+{0..3}
    uint2 raw = *(const uint2*)(g + (size_t)d * 16 + 4 * f4);
    float2 sf0 = __half22float2(*(__half2*)&raw.x);
    float2 sf1 = __half22float2(*(__half2*)&raw.y);
    float di = dinv[d];
    float h0 = fmaxf(di * (ax + sf0.x) + b1s[4 * f4 + 0], 0.f);
    float h1 = fmaxf(di * (ay + sf0.y) + b1s[4 * f4 + 1], 0.f);
    float h2 = fmaxf(di * (az + sf1.x) + b1s[4 * f4 + 2], 0.f);
    float h3 = fmaxf(di * (aw + sf1.y) + b1s[4 * f4 + 3], 0.f);
    // fused xform2: g2[d,f] = fp16( (h @ W2)[f] * dinv[d] ), lanes 0..15
    int f = lane & 15;
    float acc = 0.f;
#pragma unroll
    for (int k = 0; k < 16; ++k) {
        float src = ((k & 3) == 0) ? h0 : ((k & 3) == 1) ? h1 : ((k & 3) == 2) ? h2 : h3;
        float hv = __shfl(src, k >> 2);
        acc += hv * w2s[k * 16 + f];
    }
    if (lane < 16)
        g2[(size_t)d * 16 + f] = __float2half_rn(acc * di);
}

// Layer-2 aggregation + fused final linear.
// Epilogue: h2 = relu(dinv*(sum+self)+b2); out[d,:] = h2 @ W_lin + b_lin,
// 2 output features per lane (128 total), coalesced 512B store per wave.
__global__ __launch_bounds__(256) void k_aggr2(const __half* __restrict__ g,
                                               const int* __restrict__ row_start,
                                               const int* __restrict__ row_end,
                                               const int* __restrict__ csr_src,
                                               const float* __restrict__ dinv,
                                               const float* __restrict__ b2,
                                               const float* __restrict__ Wl,
                                               const float* __restrict__ bl,
                                               float* __restrict__ out, int N) {
    __shared__ float wls[16 * 128];
    __shared__ float bls[128];
    __shared__ float b2s[16];
    int t = threadIdx.x;
    const v4f* w4 = (const v4f*)Wl;
    for (int idx = t; idx < 512; idx += 256) ((v4f*)wls)[idx] = w4[idx];
    if (t < 128) bls[t] = bl[t];
    if (t < 16)  b2s[t] = b2[t];
    __syncthreads();
    int wave = t >> 6, lane = t & 63;
    int d = blockIdx.x * 4 + wave;
    if (d >= N) return;
    int grp = lane >> 2, f4 = lane & 3;
    int s0 = row_start[d], s1 = row_end[d];
    float ax = 0.f, ay = 0.f, az = 0.f, aw = 0.f;
    for (int i = s0 + grp; i < s1; i += 32) {
        int sa = __builtin_nontemporal_load(csr_src + i);
        int ib = i + 16;
        bool two = (ib < s1);
        int sb = two ? __builtin_nontemporal_load(csr_src + ib) : 0;
        uint2 ra = *(const uint2*)(g + (size_t)sa * 16 + 4 * f4);
        uint2 rb;
        if (two) rb = *(const uint2*)(g + (size_t)sb * 16 + 4 * f4);
        float2 a0 = __half22float2(*(__half2*)&ra.x);
        float2 a1 = __half22float2(*(__half2*)&ra.y);
        ax += a0.x; ay += a0.y; az += a1.x; aw += a1.y;
        if (two) {
            float2 c0 = __half22float2(*(__half2*)&rb.x);
            float2 c1 = __half22float2(*(__half2*)&rb.y);
            ax += c0.x; ay += c0.y; az += c1.x; aw += c1.y;
        }
    }
#pragma unroll
    for (int off = 4; off <= 32; off <<= 1) {
        ax += __shfl_xor(ax, off);
        ay += __shfl_xor(ay, off);
        az += __shfl_xor(az, off);
        aw += __shfl_xor(aw, off);
    }
    uint2 raw = *(const uint2*)(g + (size_t)d * 16 + 4 * f4);
    float2 sf0 = __half22float2(*(__half2*)&raw.x);
    float2 sf1 = __half22float2(*(__half2*)&raw.y);
    float di = dinv[d];
    float h0 = fmaxf(di * (ax + sf0.x) + b2s[4 * f4 + 0], 0.f);
    float h1 = fmaxf(di * (ay + sf0.y) + b2s[4 * f4 + 1], 0.f);
    float h2 = fmaxf(di * (az + sf1.x) + b2s[4 * f4 + 2], 0.f);
    float h3 = fmaxf(di * (aw + sf1.y) + b2s[4 * f4 + 3], 0.f);
    // fused final: out[d, 2*lane .. 2*lane+1]
    float o0 = bls[2 * lane], o1 = bls[2 * lane + 1];
#pragma unroll
    for (int k = 0; k < 16; ++k) {
        float src = ((k & 3) == 0) ? h0 : ((k & 3) == 1) ? h1 : ((k & 3) == 2) ? h2 : h3;
        float hv = __shfl(src, k >> 2);
        o0 += hv * wls[k * 128 + 2 * lane];
        o1 += hv * wls[k * 128 + 2 * lane + 1];
    }
    v2f o; o.x = o0; o.y = o1;
    __builtin_nontemporal_store(o, (v2f*)(out + (size_t)d * 128 + 2 * lane));
}

extern "C" void kernel_launch(void* const* d_in, const int* in_sizes, int n_in,
                              void* d_out, int out_size, void* d_ws, size_t ws_size,
                              hipStream_t stream) {
    const float* x  = (const float*)d_in[0];
    const int*   ei = (const int*)d_in[1];
    const float* W1 = (const float*)d_in[2];
    const float* b1 = (const float*)d_in[3];
    const float* W2 = (const float*)d_in[4];
    const float* b2 = (const float*)d_in[5];
    const float* Wl = (const float*)d_in[6];
    const float* bl = (const float*)d_in[7];
    float*       out = (float*)d_out;

    const int N = in_sizes[0] / 128;
    const int E = in_sizes[1] / 2;
    const int NB = (N + NPB - 1) >> NPB_SHIFT;   // buckets used (<= NB_MAX)

    char* ws = (char*)d_ws;
    auto carve = [&](size_t bytes) {
        char* p = ws;
        ws += (bytes + 255) & ~(size_t)255;
        return p;
    };
    int*   bucket_cnt  = (int*)carve((size_t)NB_MAX * 4);
    int*   bucket_base = (int*)carve((size_t)NB_MAX * 4);
    int*   bucket_cur  = (int*)carve((size_t)NB_MAX * 4);
    float* dinv        = (float*)carve((size_t)N * 4);
    int*   row_start   = (int*)carve((size_t)N * 4);
    int*   row_end     = (int*)carve((size_t)N * 4);
    int*   csr_src     = (int*)carve(((size_t)E + 16 * NB_MAX) * 4);
    // pairs dead after k_build -> alias g1(fp16)+g2(fp16) onto it
    size_t pairs_bytes = ((size_t)E + 16 * NB_MAX) * 4;
    size_t g_off       = ((size_t)N * 16 * 2 + 255) & ~(size_t)255;
    size_t gh_bytes    = g_off * 2;
    size_t union_bytes = pairs_bytes > gh_bytes ? pairs_bytes : gh_bytes;
    int*    pairs = (int*)carve(union_bytes);
    __half* g1    = (__half*)pairs;
    __half* g2    = (__half*)((char*)pairs + g_off);
    (void)ws_size; (void)n_in; (void)out_size;

    const int TB = 256;
    // bucketed edge partition + CSR (shared by both layers)
    k_zero_buckets<<<1, NB_MAX, 0, stream>>>(bucket_cnt);
    k_bucket_cnt<<<512, TB, 0, stream>>>(ei, bucket_cnt, E);
    k_bucket_scan<<<1, NB_MAX, 0, stream>>>(bucket_cnt, bucket_base, bucket_cur);
    k_partition<<<(E + PART_TILE - 1) / PART_TILE, PART_THR, 0, stream>>>(ei, bucket_cur, pairs, E);
    k_build<<<NB, TB, 0, stream>>>(pairs, bucket_cnt, bucket_base, row_start, row_end, dinv, csr_src, N);
    // layer 1 transform
    k_xform1<<<(N + 15) / 16, TB, 0, stream>>>(x, W1, dinv, g1, N);
    // layer 1 aggregate + fused layer-2 transform
    k_aggr1<<<(N + 3) / 4, TB, 0, stream>>>(g1, row_start, row_end, csr_src, dinv, b1, W2, g2, N);
    // layer 2 aggregate + fused final linear
    k_aggr2<<<(N + 3) / 4, TB, 0, stream>>>(g2, row_start, row_end, csr_src, dinv, b2, Wl, bl, out, N);
}

// Round 8
// 270.309 us; speedup vs baseline: 3.4187x; 1.1938x over previous
//
#include <hip/hip_runtime.h>
#include <hip/hip_fp16.h>

// ---------------------------------------------------------------------------
// GCN forward: h1 = relu(GCNConv(x, W1, b1)); h2 = relu(GCNConv(h1, W2, b2));
// out = h2 @ W_lin + b_lin
// N=100000, E=3200000, F_in=128, H=16, F_out=128.
// edge_index arrives as int32 [2*E]: row 0 = src, row 1 = dst.
//
// R8 pipeline (memset + 7 kernels, NO CSR):
//   memset(bucket_cnt) -> bucket_cnt -> scan -> partition (packed pairs,
//   bucket-contiguous) -> deg (per-bucket hist -> dinv) -> xform1
//   -> aggr1e: block per bucket, edge-parallel, FIXED-POINT int LDS
//      accumulators (native ds_add, no CAS loop -- R5 lesson), epilogue
//      fuses relu+W2 at BUCKET granularity (R7 lesson) -> g2 fp16
//   -> aggr2e: same gather, epilogue fuses relu+W_lin+b_lin -> out.
// Fixed-point scale 2^18: quantization 3.8e-6/edge << fp16 4.9e-4; int sums
// are exact & order-independent (deterministic). Overflow margin ~19x.
// ---------------------------------------------------------------------------

typedef int   v4i __attribute__((ext_vector_type(4)));
typedef float v4f __attribute__((ext_vector_type(4)));
typedef float v2f __attribute__((ext_vector_type(2)));

#define NPB        256    // nodes per bucket
#define NPB_SHIFT  8
#define NB_MAX     512    // max buckets
#define PART_TILE  8192   // edges per partition block
#define PART_THR   1024
#define PT_ITERS   (PART_TILE / 4 / PART_THR)   // = 2 quads/thread
#define AGG_STAGE  2048   // pairs staged per aggregation tile
#define FXSCALE    262144.0f          // 2^18
#define FXINV      (1.0f / 262144.0f)

// Per-block LDS histogram of dst>>8, int4 loads, flushed once per block.
__global__ __launch_bounds__(256) void k_bucket_cnt(const int* __restrict__ ei,
                                                    int* __restrict__ bucket_cnt, int E) {
    __shared__ int h[NB_MAX];
    int t = threadIdx.x;
    for (int j = t; j < NB_MAX; j += 256) h[j] = 0;
    __syncthreads();
    const v4i* d4 = (const v4i*)(ei + E);
    int EQ = E >> 2;
    for (int q = blockIdx.x * 256 + t; q < EQ; q += gridDim.x * 256) {
        v4i dd = __builtin_nontemporal_load(d4 + q);
        atomicAdd(&h[dd.x >> NPB_SHIFT], 1);
        atomicAdd(&h[dd.y >> NPB_SHIFT], 1);
        atomicAdd(&h[dd.z >> NPB_SHIFT], 1);
        atomicAdd(&h[dd.w >> NPB_SHIFT], 1);
    }
    if (blockIdx.x == 0) {
        for (int e = (EQ << 2) + t; e < E; e += 256)
            atomicAdd(&h[ei[E + e] >> NPB_SHIFT], 1);
    }
    __syncthreads();
    for (int j = t; j < NB_MAX; j += 256)
        if (h[j]) atomicAdd(&bucket_cnt[j], h[j]);
}

// Exclusive scan of padded counts (pad to 16 pairs: 64B-aligned regions).
__global__ __launch_bounds__(NB_MAX) void k_bucket_scan(const int* __restrict__ bucket_cnt,
                                                        int* __restrict__ bucket_base,
                                                        int* __restrict__ bucket_cur) {
    __shared__ int s[NB_MAX];
    int t = threadIdx.x;
    int padded = (bucket_cnt[t] + 15) & ~15;
    s[t] = padded;
    __syncthreads();
    for (int off = 1; off < NB_MAX; off <<= 1) {
        int v = (t >= off) ? s[t - off] : 0;
        __syncthreads();
        s[t] += v;
        __syncthreads();
    }
    int excl = s[t] - padded;
    bucket_base[t] = excl;
    bucket_cur[t]  = excl;
}

// Partition edges into bucket-contiguous packed (src<<8 | dstlocal) runs.
__global__ __launch_bounds__(PART_THR) void k_partition(const int* __restrict__ ei,
                                                        int* __restrict__ bucket_cur,
                                                        int* __restrict__ pairs, int E) {
    __shared__ int h[NB_MAX];    // pass1: local hist; pass2: local cursor
    __shared__ int rb[NB_MAX];   // run base (absolute) per bucket
    int t = threadIdx.x;
    const v4i* s4 = (const v4i*)ei;
    const v4i* d4 = (const v4i*)(ei + E);
    int EQ = E >> 2;
    int q0 = blockIdx.x * (PART_TILE / 4);
    bool last = (blockIdx.x == gridDim.x - 1);
    v4i dsave[PT_ITERS];

    for (int j = t; j < NB_MAX; j += PART_THR) h[j] = 0;
    __syncthreads();
#pragma unroll
    for (int it = 0; it < PT_ITERS; ++it) {
        int q = q0 + it * PART_THR + t;
        v4i dd;
        if (q < EQ) {
            dd = __builtin_nontemporal_load(d4 + q);
            atomicAdd(&h[dd.x >> NPB_SHIFT], 1);
            atomicAdd(&h[dd.y >> NPB_SHIFT], 1);
            atomicAdd(&h[dd.z >> NPB_SHIFT], 1);
            atomicAdd(&h[dd.w >> NPB_SHIFT], 1);
        }
        dsave[it] = dd;
    }
    if (last) {
        for (int e = (EQ << 2) + t; e < E; e += PART_THR)
            atomicAdd(&h[ei[E + e] >> NPB_SHIFT], 1);
    }
    __syncthreads();
    for (int j = t; j < NB_MAX; j += PART_THR) {
        int c = h[j];
        rb[j] = c ? atomicAdd(&bucket_cur[j], c) : 0;
        h[j] = 0;
    }
    __syncthreads();
#pragma unroll
    for (int it = 0; it < PT_ITERS; ++it) {
        int q = q0 + it * PART_THR + t;
        if (q < EQ) {
            v4i ss = __builtin_nontemporal_load(s4 + q);
            v4i dd = dsave[it];
#pragma unroll
            for (int k = 0; k < 4; ++k) {
                int s = ss[k], d = dd[k];
                int b = d >> NPB_SHIFT;
                int pos = rb[b] + atomicAdd(&h[b], 1);
                pairs[pos] = (s << NPB_SHIFT) | (d & (NPB - 1));
            }
        }
    }
    if (last) {
        for (int e = (EQ << 2) + t; e < E; e += PART_THR) {
            int s = ei[e], d = ei[E + e];
            int b = d >> NPB_SHIFT;
            int pos = rb[b] + atomicAdd(&h[b], 1);
            pairs[pos] = (s << NPB_SHIFT) | (d & (NPB - 1));
        }
    }
}

// One block per bucket: int LDS deg hist -> dinv (deg+1 self-loop).
__global__ __launch_bounds__(256) void k_deg(const int* __restrict__ pairs,
                                             const int* __restrict__ bucket_cnt,
                                             const int* __restrict__ bucket_base,
                                             float* __restrict__ dinv, int N) {
    __shared__ int deg[NPB];
    int b = blockIdx.x, t = threadIdx.x;
    int cnt  = bucket_cnt[b];
    int base = bucket_base[b];   // 16-aligned
    deg[t] = 0;
    __syncthreads();
    const v4i* p4 = (const v4i*)(pairs + base);
    int cq = cnt >> 2;
    for (int q = t; q < cq; q += 256) {
        v4i pp = __builtin_nontemporal_load(p4 + q);
        atomicAdd(&deg[pp.x & (NPB - 1)], 1);
        atomicAdd(&deg[pp.y & (NPB - 1)], 1);
        atomicAdd(&deg[pp.z & (NPB - 1)], 1);
        atomicAdd(&deg[pp.w & (NPB - 1)], 1);
    }
    for (int i = (cq << 2) + t; i < cnt; i += 256)
        atomicAdd(&deg[pairs[base + i] & (NPB - 1)], 1);
    __syncthreads();
    int n = (b << NPB_SHIFT) + t;
    if (n < N) dinv[n] = rsqrtf((float)(deg[t] + 1));
}

// g1[n,:] = fp16( (x[n,:] @ W1) * dinv[n] )   (128 -> 16), 16 nodes per block
__global__ __launch_bounds__(256) void k_xform1(const float* __restrict__ x,
                                                const float* __restrict__ W1,
                                                const float* __restrict__ dinv,
                                                __half* __restrict__ g, int N) {
    __shared__ float xs[16][132];
    __shared__ float ws[128 * 16];
    int t = threadIdx.x;
    int n0 = blockIdx.x * 16;
    const v4f* w4 = (const v4f*)W1;
    const v4f* x4 = (const v4f*)x;
    for (int idx = t; idx < 512; idx += 256) ((v4f*)ws)[idx] = w4[idx];
    for (int idx = t; idx < 512; idx += 256) {
        int r = idx >> 5, c4 = idx & 31;
        int n = n0 + r;
        v4f v = (n < N) ? x4[(size_t)n * 32 + c4] : (v4f)(0.f);
        *(v4f*)&xs[r][c4 * 4] = v;
    }
    __syncthreads();
    int node = t >> 4, f = t & 15;
    int n = n0 + node;
    if (n < N) {
        float sum = 0.f;
#pragma unroll
        for (int k = 0; k < 128; ++k) sum += xs[node][k] * ws[k * 16 + f];
        g[(size_t)n * 16 + f] = __float2half_rn(sum * dinv[n]);
    }
}

// Layer-1: edge-parallel fixed-point aggregation + bucket-level W2 epilogue.
// g2[d,:] = fp16( relu(dinv*(sum+self)+b1) @ W2 * dinv )
__global__ __launch_bounds__(1024) void k_aggr1e(const __half* __restrict__ g1,
                                                 const int* __restrict__ pairs,
                                                 const int* __restrict__ bucket_cnt,
                                                 const int* __restrict__ bucket_base,
                                                 const float* __restrict__ dinv,
                                                 const float* __restrict__ b1,
                                                 const float* __restrict__ W2,
                                                 __half* __restrict__ g2, int N) {
    __shared__ int   acc[NPB * 17];     // stride 17: spread banks; also h1 (float) later
    __shared__ int   stage[AGG_STAGE];
    __shared__ float w2s[256];
    __shared__ float b1s[16];
    int t = threadIdx.x, b = blockIdx.x;
    int n0 = b << NPB_SHIFT;
    int cnt  = bucket_cnt[b];
    int base = bucket_base[b];
    if (t < 256) w2s[t] = W2[t];
    if (t < 16)  b1s[t] = b1[t];
    for (int i = t; i < NPB * 17; i += 1024) acc[i] = 0;
    __syncthreads();
    int es = t >> 3, f2 = t & 7;
    for (int off = 0; off < cnt; off += AGG_STAGE) {
        int m = min(AGG_STAGE, cnt - off);
        if (t < m) stage[t] = __builtin_nontemporal_load(pairs + base + off + t);
        if (t + 1024 < m) stage[t + 1024] = __builtin_nontemporal_load(pairs + base + off + t + 1024);
        __syncthreads();
        for (int e = es; e < m; e += 128) {
            int p = stage[e];
            int s = p >> NPB_SHIFT, dl = p & (NPB - 1);
            float2 fv = __half22float2(*(const __half2*)(g1 + (size_t)s * 16 + 2 * f2));
            atomicAdd(&acc[dl * 17 + 2 * f2],     __float2int_rn(fv.x * FXSCALE));
            atomicAdd(&acc[dl * 17 + 2 * f2 + 1], __float2int_rn(fv.y * FXSCALE));
        }
        __syncthreads();
    }
    // phase A: acc -> h1 in place (each slot touched by exactly one thread)
#pragma unroll
    for (int r = 0; r < 4; ++r) {
        int idx = r * 1024 + t;          // 4096 = 256*16
        int d = idx >> 4, f = idx & 15;
        int n = n0 + d;
        float hv = 0.f;
        if (n < N) {
            float sum  = (float)acc[d * 17 + f] * FXINV;
            float self = __half2float(g1[(size_t)n * 16 + f]);
            hv = fmaxf(dinv[n] * (sum + self) + b1s[f], 0.f);
        }
        acc[d * 17 + f] = __float_as_int(hv);
    }
    __syncthreads();
    // phase B: g2 = fp16((h1 @ W2) * dinv), 2048 half2 outputs
#pragma unroll
    for (int r = 0; r < 2; ++r) {
        int idx2 = r * 1024 + t;         // 2048 = 256*8
        int d = idx2 >> 3, ff = idx2 & 7;
        int n = n0 + d;
        if (n < N) {
            float sx = 0.f, sy = 0.f;
#pragma unroll
            for (int k = 0; k < 16; ++k) {
                float hv = __int_as_float(acc[d * 17 + k]);
                sx += hv * w2s[k * 16 + 2 * ff];
                sy += hv * w2s[k * 16 + 2 * ff + 1];
            }
            float di = dinv[n];
            *(__half2*)(g2 + (size_t)n * 16 + 2 * ff) = __floats2half2_rn(sx * di, sy * di);
        }
    }
}

// Layer-2: edge-parallel fixed-point aggregation + bucket-level final GEMM.
// out[d,:] = relu(dinv*(sum+self)+b2) @ W_lin + b_lin
__global__ __launch_bounds__(1024) void k_aggr2e(const __half* __restrict__ g2,
                                                 const int* __restrict__ pairs,
                                                 const int* __restrict__ bucket_cnt,
                                                 const int* __restrict__ bucket_base,
                                                 const float* __restrict__ dinv,
                                                 const float* __restrict__ b2,
                                                 const float* __restrict__ Wl,
                                                 const float* __restrict__ bl,
                                                 float* __restrict__ out, int N) {
    __shared__ int   acc[NPB * 17];
    __shared__ int   stage[AGG_STAGE];
    __shared__ float wls[16 * 128];
    __shared__ float bls[128];
    __shared__ float b2s[16];
    int t = threadIdx.x, b = blockIdx.x;
    int n0 = b << NPB_SHIFT;
    int cnt  = bucket_cnt[b];
    int base = bucket_base[b];
    if (t < 512) ((v4f*)wls)[t] = ((const v4f*)Wl)[t];
    if (t < 128) bls[t] = bl[t];
    if (t < 16)  b2s[t] = b2[t];
    for (int i = t; i < NPB * 17; i += 1024) acc[i] = 0;
    __syncthreads();
    int es = t >> 3, f2 = t & 7;
    for (int off = 0; off < cnt; off += AGG_STAGE) {
        int m = min(AGG_STAGE, cnt - off);
        if (t < m) stage[t] = __builtin_nontemporal_load(pairs + base + off + t);
        if (t + 1024 < m) stage[t + 1024] = __builtin_nontemporal_load(pairs + base + off + t + 1024);
        __syncthreads();
        for (int e = es; e < m; e += 128) {
            int p = stage[e];
            int s = p >> NPB_SHIFT, dl = p & (NPB - 1);
            float2 fv = __half22float2(*(const __half2*)(g2 + (size_t)s * 16 + 2 * f2));
            atomicAdd(&acc[dl * 17 + 2 * f2],     __float2int_rn(fv.x * FXSCALE));
            atomicAdd(&acc[dl * 17 + 2 * f2 + 1], __float2int_rn(fv.y * FXSCALE));
        }
        __syncthreads();
    }
    // phase A: acc -> h2 in place
#pragma unroll
    for (int r = 0; r < 4; ++r) {
        int idx = r * 1024 + t;
        int d = idx >> 4, f = idx & 15;
        int n = n0 + d;
        float hv = 0.f;
        if (n < N) {
            float sum  = (float)acc[d * 17 + f] * FXINV;
            float self = __half2float(g2[(size_t)n * 16 + f]);
            hv = fmaxf(dinv[n] * (sum + self) + b2s[f], 0.f);
        }
        acc[d * 17 + f] = __float_as_int(hv);
    }
    __syncthreads();
    // phase B: out = h2 @ W_lin + b_lin; 16384 float2 outputs, coalesced
    const v2f* wl2 = (const v2f*)wls;
#pragma unroll
    for (int r = 0; r < 16; ++r) {
        int idx2 = r * 1024 + t;         // 16384 = 256*64
        int d = idx2 >> 6, fc = idx2 & 63;
        int n = n0 + d;
        if (n < N) {
            float ox = bls[2 * fc], oy = bls[2 * fc + 1];
#pragma unroll
            for (int k = 0; k < 16; ++k) {
                float hv = __int_as_float(acc[d * 17 + k]);
                v2f w = wl2[k * 64 + fc];
                ox += hv * w.x;
                oy += hv * w.y;
            }
            v2f o; o.x = ox; o.y = oy;
            __builtin_nontemporal_store(o, (v2f*)(out + (size_t)n * 128 + 2 * fc));
        }
    }
}

extern "C" void kernel_launch(void* const* d_in, const int* in_sizes, int n_in,
                              void* d_out, int out_size, void* d_ws, size_t ws_size,
                              hipStream_t stream) {
    const float* x  = (const float*)d_in[0];
    const int*   ei = (const int*)d_in[1];
    const float* W1 = (const float*)d_in[2];
    const float* b1 = (const float*)d_in[3];
    const float* W2 = (const float*)d_in[4];
    const float* b2 = (const float*)d_in[5];
    const float* Wl = (const float*)d_in[6];
    const float* bl = (const float*)d_in[7];
    float*       out = (float*)d_out;

    const int N = in_sizes[0] / 128;
    const int E = in_sizes[1] / 2;
    const int NB = (N + NPB - 1) >> NPB_SHIFT;   // buckets used (<= NB_MAX)

    char* ws = (char*)d_ws;
    auto carve = [&](size_t bytes) {
        char* p = ws;
        ws += (bytes + 255) & ~(size_t)255;
        return p;
    };
    int*    bucket_cnt  = (int*)carve((size_t)NB_MAX * 4);
    int*    bucket_base = (int*)carve((size_t)NB_MAX * 4);
    int*    bucket_cur  = (int*)carve((size_t)NB_MAX * 4);
    float*  dinv        = (float*)carve((size_t)N * 4);
    int*    pairs       = (int*)carve(((size_t)E + 16 * NB_MAX) * 4);
    __half* g1          = (__half*)carve((size_t)N * 16 * 2);
    __half* g2          = (__half*)carve((size_t)N * 16 * 2);
    (void)ws_size; (void)n_in; (void)out_size;

    hipMemsetAsync(bucket_cnt, 0, (size_t)NB_MAX * 4, stream);
    k_bucket_cnt<<<512, 256, 0, stream>>>(ei, bucket_cnt, E);
    k_bucket_scan<<<1, NB_MAX, 0, stream>>>(bucket_cnt, bucket_base, bucket_cur);
    k_partition<<<(E + PART_TILE - 1) / PART_TILE, PART_THR, 0, stream>>>(ei, bucket_cur, pairs, E);
    k_deg<<<NB, 256, 0, stream>>>(pairs, bucket_cnt, bucket_base, dinv, N);
    k_xform1<<<(N + 15) / 16, 256, 0, stream>>>(x, W1, dinv, g1, N);
    k_aggr1e<<<NB, 1024, 0, stream>>>(g1, pairs, bucket_cnt, bucket_base, dinv, b1, W2, g2, N);
    k_aggr2e<<<NB, 1024, 0, stream>>>(g2, pairs, bucket_cnt, bucket_base, dinv, b2, Wl, bl, out, N);
}